// Round 2
// baseline (511.105 us; speedup 1.0000x reference)
//
#include <hip/hip_runtime.h>
#include <cfloat>

#define DIM       2048
#define N_EXPERTS 64
#define TPW       8     // tokens per wave
#define WAVES     4     // waves per block
#define TPB       (TPW * WAVES)  // 32 tokens per block

__global__ __launch_bounds__(256, 2)
void topk_gate_kernel(const float* __restrict__ x,
                      const float* __restrict__ W,
                      const float* __restrict__ b,
                      float* __restrict__ out)
{
    const int tid     = threadIdx.x;
    const int lane    = tid & 63;
    const int wave    = tid >> 6;
    const int blk_tok = blockIdx.x * TPB;

    // Wave-uniform token base, forced uniform via readfirstlane so the
    // x loads are provably non-divergent -> backend selects s_load (SMEM,
    // scalar pipe) instead of LDS/vector broadcast. x values land in SGPRs
    // and feed v_fma_f32 as the one allowed scalar operand.
    const int utok0 = __builtin_amdgcn_readfirstlane(blk_tok + wave * TPW);

    // lane == expert: this lane owns W row `lane` (streamed from global, L1/L2 hot)
    const float* wrow = W + (size_t)lane * DIM;
    const float  bias = b[lane];

    double accd[TPW];
    #pragma unroll
    for (int t = 0; t < TPW; ++t) accd[t] = 0.0;

    for (int k0 = 0; k0 < DIM; k0 += 32) {
        // fp32 sub-block accumulators, flushed to f64 every 32 k's
        float accf[TPW];
        #pragma unroll
        for (int t = 0; t < TPW; ++t) accf[t] = 0.f;

        #pragma unroll
        for (int k4 = 0; k4 < 32; k4 += 4) {
            float4 wv = *(const float4*)(wrow + k0 + k4);
            #pragma unroll
            for (int t = 0; t < TPW; ++t) {
                // uniform address (utok0, k0, k4 all wave-uniform) -> s_load_dwordx4
                const float* xr = x + (size_t)(utok0 + t) * DIM + k0 + k4;
                float x0 = xr[0];
                float x1 = xr[1];
                float x2 = xr[2];
                float x3 = xr[3];
                accf[t] = fmaf(x0, wv.x, accf[t]);
                accf[t] = fmaf(x1, wv.y, accf[t]);
                accf[t] = fmaf(x2, wv.z, accf[t]);
                accf[t] = fmaf(x3, wv.w, accf[t]);
            }
        }

        #pragma unroll
        for (int t = 0; t < TPW; ++t) accd[t] += (double)accf[t];
    }

    // Epilogue: per token, top-2 across the 64 lanes (lane = expert)
    #pragma unroll
    for (int t = 0; t < TPW; ++t) {
        float s = (float)accd[t] + bias;

        // argmax with lower-index tie-break (matches lax.top_k stability)
        float v = s; int i = lane;
        #pragma unroll
        for (int off = 32; off > 0; off >>= 1) {
            float ov = __shfl_xor(v, off, 64);
            int   oi = __shfl_xor(i, off, 64);
            if (ov > v || (ov == v && oi < i)) { v = ov; i = oi; }
        }
        float m1 = v; int i1 = i;

        float s2 = (lane == i1) ? -FLT_MAX : s;
        v = s2; i = lane;
        #pragma unroll
        for (int off = 32; off > 0; off >>= 1) {
            float ov = __shfl_xor(v, off, 64);
            int   oi = __shfl_xor(i, off, 64);
            if (ov > v || (ov == v && oi < i)) { v = ov; i = oi; }
        }
        float m2 = v; int i2 = i;

        // weights: softmax masked to top-2, renormalized -> denominator cancels
        float e   = __expf(m2 - m1);     // in (0, 1]
        float inv = 1.f / (1.f + e);
        float w1  = inv;
        float w2  = e * inv;

        float outv = (lane == i1) ? w1 : ((lane == i2) ? w2 : 0.f);
        out[(size_t)(utok0 + t) * N_EXPERTS + lane] = outv;
    }
}

extern "C" void kernel_launch(void* const* d_in, const int* in_sizes, int n_in,
                              void* d_out, int out_size, void* d_ws, size_t ws_size,
                              hipStream_t stream) {
    const float* x = (const float*)d_in[0];
    const float* W = (const float*)d_in[1];
    const float* b = (const float*)d_in[2];
    float* out = (float*)d_out;

    const int n_tokens = in_sizes[0] / DIM;   // 16384
    dim3 grid(n_tokens / TPB);                // 512 blocks
    dim3 block(256);
    topk_gate_kernel<<<grid, block, 0, stream>>>(x, W, b, out);
}

// Round 3
// 336.939 us; speedup vs baseline: 1.5169x; 1.5169x over previous
//
#include <hip/hip_runtime.h>
#include <cfloat>

#define DIM   2048
#define NE    64
#define TPB   32          // tokens per block
#define WIN   256         // k-window staged in LDS
#define NWIN  (DIM / WIN) // 8

// DPP-based cross-lane add (VALU pipe, not LDS). CTRL must be immediate.
template <int CTRL>
__device__ __forceinline__ float dpp_add(float v) {
    int p = __builtin_amdgcn_update_dpp(0, __float_as_int(v), CTRL, 0xf, 0xf, true);
    return v + __int_as_float(p);
}

__launch_bounds__(256, 2)
__global__ void topk_gate_kernel(const float* __restrict__ x,
                                 const float* __restrict__ W,
                                 const float* __restrict__ b,
                                 float* __restrict__ out)
{
    // 2 x 32 x 256 floats = exactly 64 KB; epilogue grid aliases buffer 0.
    __shared__ float xs[2][TPB][WIN];

    const int tid  = threadIdx.x;
    const int lane = tid & 63;
    const int wave = tid >> 6;        // 0..3
    const int ks   = lane & 15;       // k-slice within window sub-block
    const int el   = lane >> 4;       // expert octet group 0..3
    const int tok0 = blockIdx.x * TPB;

    const int tg = (wave >> 1) * 16;  // token group base (0 or 16)
    const int eh = (wave & 1) * 32;   // expert half base (0 or 32)

    float acc[16][8];
    #pragma unroll
    for (int t = 0; t < 16; ++t)
        #pragma unroll
        for (int j = 0; j < 8; ++j) acc[t][j] = 0.f;

    const float bias = b[lane];

    // ---- stage window 0 ----
    {
        #pragma unroll
        for (int rr = 0; rr < 8; ++rr) {
            const int r = wave * 8 + rr;
            const float* g = x + (size_t)(tok0 + r) * DIM + 0 * WIN + lane * 4;
#if __has_builtin(__builtin_amdgcn_global_load_lds)
            __builtin_amdgcn_global_load_lds(
                (const __attribute__((address_space(1))) unsigned int*)g,
                (__attribute__((address_space(3))) unsigned int*)&xs[0][r][0],
                16, 0, 0);
#else
            float4 v = *(const float4*)g;
            *(float4*)&xs[0][r][lane * 4] = v;
#endif
        }
    }
    __syncthreads();  // inserts s_waitcnt vmcnt(0) before s_barrier -> data visible

    // ---- main loop over k windows, double-buffered ----
    for (int m = 0; m < NWIN; ++m) {
        const int buf = m & 1;

        if (m + 1 < NWIN) {  // prefetch next window into the other buffer
            #pragma unroll
            for (int rr = 0; rr < 8; ++rr) {
                const int r = wave * 8 + rr;
                const float* g = x + (size_t)(tok0 + r) * DIM + (m + 1) * WIN + lane * 4;
#if __has_builtin(__builtin_amdgcn_global_load_lds)
                __builtin_amdgcn_global_load_lds(
                    (const __attribute__((address_space(1))) unsigned int*)g,
                    (__attribute__((address_space(3))) unsigned int*)&xs[buf ^ 1][r][0],
                    16, 0, 0);
#else
                float4 v = *(const float4*)g;
                *(float4*)&xs[buf ^ 1][r][lane * 4] = v;
#endif
            }
        }

        #pragma unroll
        for (int p = 0; p < 4; ++p) {
            const int ko = m * WIN + p * 64 + ks * 4;  // this lane's k offset
            float4 wv[8];
            #pragma unroll
            for (int j = 0; j < 8; ++j)
                wv[j] = *(const float4*)(W + (size_t)(eh + el * 8 + j) * DIM + ko);

            #pragma unroll
            for (int t = 0; t < 16; ++t) {
                float4 xv = *(const float4*)&xs[buf][tg + t][p * 64 + ks * 4];
                #pragma unroll
                for (int j = 0; j < 8; ++j) {
                    acc[t][j] = fmaf(xv.x, wv[j].x, acc[t][j]);
                    acc[t][j] = fmaf(xv.y, wv[j].y, acc[t][j]);
                    acc[t][j] = fmaf(xv.z, wv[j].z, acc[t][j]);
                    acc[t][j] = fmaf(xv.w, wv[j].w, acc[t][j]);
                }
            }
        }
        __syncthreads();
    }

    // ---- reduce partial dots over the 16 ks lanes (DPP, VALU pipe) ----
    // lanes [el*16 .. el*16+15] form a DPP row-of-16; butterfly xor1/2/4/8.
    #pragma unroll
    for (int t = 0; t < 16; ++t)
        #pragma unroll
        for (int j = 0; j < 8; ++j) {
            float v = acc[t][j];
            v = dpp_add<0xB1>(v);   // quad_perm [1,0,3,2] : xor 1
            v = dpp_add<0x4E>(v);   // quad_perm [2,3,0,1] : xor 2
            v = dpp_add<0x141>(v);  // row_half_mirror     : xor 4
            v = dpp_add<0x140>(v);  // row_mirror          : xor 8
            acc[t][j] = v;          // all 16 ks lanes now hold the sum
        }

    // ---- scatter scores into block-level grid [TPB][68] (aliases xs[0]) ----
    float* grid = &xs[0][0][0];
    #pragma unroll
    for (int t = 0; t < 16; ++t) {
        if (ks == t) {  // one writer lane per (row-of-16, token)
            float* grow = grid + (size_t)(tg + t) * 68 + eh + el * 8;
            *(float4*)(grow)     = make_float4(acc[t][0], acc[t][1], acc[t][2], acc[t][3]);
            *(float4*)(grow + 4) = make_float4(acc[t][4], acc[t][5], acc[t][6], acc[t][7]);
        }
    }
    __syncthreads();

    // ---- per-token top-2 + renormalized softmax weights (R1-proven epilogue) ----
    #pragma unroll
    for (int tt = 0; tt < 8; ++tt) {
        const int t = wave * 8 + tt;
        float s = grid[t * 68 + lane] + bias;   // lane = expert

        float v = s; int i = lane;
        #pragma unroll
        for (int off = 32; off > 0; off >>= 1) {
            float ov = __shfl_xor(v, off, 64);
            int   oi = __shfl_xor(i, off, 64);
            if (ov > v || (ov == v && oi < i)) { v = ov; i = oi; }
        }
        const float m1 = v; const int i1 = i;

        float s2 = (lane == i1) ? -FLT_MAX : s;
        v = s2; i = lane;
        #pragma unroll
        for (int off = 32; off > 0; off >>= 1) {
            float ov = __shfl_xor(v, off, 64);
            int   oi = __shfl_xor(i, off, 64);
            if (ov > v || (ov == v && oi < i)) { v = ov; i = oi; }
        }
        const float m2 = v; const int i2 = i;

        const float e   = __expf(m2 - m1);
        const float inv = 1.f / (1.f + e);
        const float w1  = inv;
        const float w2  = e * inv;

        const float outv = (lane == i1) ? w1 : ((lane == i2) ? w2 : 0.f);
        out[(size_t)(tok0 + t) * NE + lane] = outv;
    }
}

extern "C" void kernel_launch(void* const* d_in, const int* in_sizes, int n_in,
                              void* d_out, int out_size, void* d_ws, size_t ws_size,
                              hipStream_t stream) {
    const float* x = (const float*)d_in[0];
    const float* W = (const float*)d_in[1];
    const float* b = (const float*)d_in[2];
    float* out = (float*)d_out;

    const int n_tokens = in_sizes[0] / DIM;   // 16384
    dim3 grid(n_tokens / TPB);                // 512 blocks
    dim3 block(256);
    topk_gate_kernel<<<grid, block, 0, stream>>>(x, W, b, out);
}

// Round 5
// 284.743 us; speedup vs baseline: 1.7950x; 1.1833x over previous
//
#include <hip/hip_runtime.h>
#include <cfloat>

#define DIM 2048
#define NE  64

typedef _Float16 half8 __attribute__((ext_vector_type(8)));
typedef float    f32x4 __attribute__((ext_vector_type(4)));

struct Split { _Float16 hi, lo; };

// Split fp32 into fp16 hi + fp16 lo where x ≈ hi + lo/2048.
// hi is clamped to 0 below fp16-min-normal so no denormal input ever
// reaches the MFMA (denorm-flush behavior then irrelevant).
__device__ __forceinline__ Split split_f32(float x) {
    Split r;
    float h32;
    if (__builtin_fabsf(x) >= 6.103515625e-05f) {
        r.hi = (_Float16)x;          // v_cvt_f16_f32 (RTN)
        h32  = (float)r.hi;
    } else {
        r.hi = (_Float16)0.0f; h32 = 0.0f;
    }
    r.lo = (_Float16)((x - h32) * 2048.0f);   // exact sub+scale, then RTN
    return r;
}

// Pre-kernel: split W [64][2048] fp32 into fragment-ordered fp16 hi/lo arrays
// in ws. Fragment order: chunk c = (kstep*4 + ntile); within chunk, lane l's
// 8 halves = W[ntile*16 + (l&15)][kstep*32 + (l>>4)*8 + 0..7].
__global__ void wsplit_kernel(const float* __restrict__ W, _Float16* __restrict__ wsb) {
    int t    = blockIdx.x * 256 + threadIdx.x;   // 0..16383
    int lane = t & 63;
    int nt   = (t >> 6) & 3;
    int sg   = t >> 8;                           // k32-step 0..63
    int e    = nt * 16 + (lane & 15);
    int k    = sg * 32 + (lane >> 4) * 8;
    const float* wp = W + (size_t)e * DIM + k;
    half8 hi, lo;
    #pragma unroll
    for (int j = 0; j < 8; ++j) {
        Split s = split_f32(wp[j]);
        hi[j] = s.hi; lo[j] = s.lo;
    }
    ((half8*)wsb)[(size_t)((sg * 4 + nt) * 64 + lane)]         = hi;
    ((half8*)wsb)[(size_t)(16384 + (sg * 4 + nt) * 64 + lane)] = lo;
}

// Main: block = 8 waves. Wave (mw, h): M-subtile mw (16 tokens), K-half h.
// Per wave: A direct from global fp32 (split in regs), B from ws fragments,
// 12 MFMAs per K32 step. Epilogue: combine K-halves in LDS, R1 top-2 shuffle.
template <bool USE_WS>
__launch_bounds__(512, 2)
__global__ void gate_mfma_kernel(const float* __restrict__ x,
                                 const float* __restrict__ W,
                                 const float* __restrict__ b,
                                 float* __restrict__ out,
                                 const _Float16* __restrict__ wsb)
{
    __shared__ float sgrid[2][64][68];   // [k-half][token][expert], +4 pad

    const int tid  = threadIdx.x;
    const int lane = tid & 63;
    const int wave = tid >> 6;
    const int mw   = wave & 3;          // M-subtile
    const int h    = wave >> 2;         // K-half
    const int tokb = blockIdx.x * 64;
    const int row  = tokb + mw * 16 + (lane & 15);
    const int kb   = h * 1024 + (lane >> 4) * 8;

    const float* aptr = x + (size_t)row * DIM + kb;

    f32x4 acch[4], accc[4];
    #pragma unroll
    for (int nt = 0; nt < 4; ++nt) {
        acch[nt] = (f32x4){0.f, 0.f, 0.f, 0.f};
        accc[nt] = (f32x4){0.f, 0.f, 0.f, 0.f};
    }

    #pragma unroll 2
    for (int s = 0; s < 32; ++s) {
        const int sg = h * 32 + s;

        // ---- A: 8 contiguous fp32 per lane, split to hi/lo fp16 ----
        f32x4 a0 = *(const f32x4*)(aptr + s * 32);
        f32x4 a1 = *(const f32x4*)(aptr + s * 32 + 4);
        half8 Ah, Al;
        #pragma unroll
        for (int j = 0; j < 4; ++j) {
            Split sp = split_f32(a0[j]);
            Ah[j] = sp.hi; Al[j] = sp.lo;
        }
        #pragma unroll
        for (int j = 0; j < 4; ++j) {
            Split sp = split_f32(a1[j]);
            Ah[4 + j] = sp.hi; Al[4 + j] = sp.lo;
        }

        // ---- B fragments ----
        half8 Bh[4], Bl[4];
        if (USE_WS) {
            const half8* wb = (const half8*)wsb;
            #pragma unroll
            for (int nt = 0; nt < 4; ++nt) {
                Bh[nt] = wb[(size_t)((sg * 4 + nt) * 64 + lane)];
                Bl[nt] = wb[(size_t)(16384 + (sg * 4 + nt) * 64 + lane)];
            }
        } else {
            #pragma unroll
            for (int nt = 0; nt < 4; ++nt) {
                const float* wp = W + (size_t)(nt * 16 + (lane & 15)) * DIM
                                    + sg * 32 + (lane >> 4) * 8;
                #pragma unroll
                for (int j = 0; j < 8; ++j) {
                    Split sp = split_f32(wp[j]);
                    Bh[nt][j] = sp.hi; Bl[nt][j] = sp.lo;
                }
            }
        }

        // ---- 12 MFMAs: hh -> acc_h ; (lo_s . hi) + (hi . lo_s) -> acc_c ----
        #pragma unroll
        for (int nt = 0; nt < 4; ++nt) {
            acch[nt] = __builtin_amdgcn_mfma_f32_16x16x32_f16(Ah, Bh[nt], acch[nt], 0, 0, 0);
            accc[nt] = __builtin_amdgcn_mfma_f32_16x16x32_f16(Al, Bh[nt], accc[nt], 0, 0, 0);
            accc[nt] = __builtin_amdgcn_mfma_f32_16x16x32_f16(Ah, Bl[nt], accc[nt], 0, 0, 0);
        }
    }

    // ---- write per-half scores to LDS: D[row=(l>>4)*4+r][col=l&15] ----
    #pragma unroll
    for (int nt = 0; nt < 4; ++nt)
        #pragma unroll
        for (int r = 0; r < 4; ++r) {
            int tl = mw * 16 + (lane >> 4) * 4 + r;
            int e  = nt * 16 + (lane & 15);
            sgrid[h][tl][e] = acch[nt][r] + accc[nt][r] * (1.0f / 2048.0f);
        }
    __syncthreads();

    // ---- per-token top-2 + renormalized softmax (R1-proven) ----
    const float bias = b[lane];
    #pragma unroll
    for (int tt = 0; tt < 8; ++tt) {
        const int t = wave * 8 + tt;
        float s = sgrid[0][t][lane] + sgrid[1][t][lane] + bias;

        float v = s; int i = lane;
        #pragma unroll
        for (int off = 32; off > 0; off >>= 1) {
            float ov = __shfl_xor(v, off, 64);
            int   oi = __shfl_xor(i, off, 64);
            if (ov > v || (ov == v && oi < i)) { v = ov; i = oi; }
        }
        const float m1 = v; const int i1 = i;

        float s2 = (lane == i1) ? -FLT_MAX : s;
        v = s2; i = lane;
        #pragma unroll
        for (int off = 32; off > 0; off >>= 1) {
            float ov = __shfl_xor(v, off, 64);
            int   oi = __shfl_xor(i, off, 64);
            if (ov > v || (ov == v && oi < i)) { v = ov; i = oi; }
        }
        const float m2 = v; const int i2 = i;

        const float e_  = __expf(m2 - m1);
        const float inv = 1.f / (1.f + e_);
        const float outv = (lane == i1) ? inv : ((lane == i2) ? e_ * inv : 0.f);
        out[(size_t)(tokb + t) * NE + lane] = outv;
    }
}

extern "C" void kernel_launch(void* const* d_in, const int* in_sizes, int n_in,
                              void* d_out, int out_size, void* d_ws, size_t ws_size,
                              hipStream_t stream) {
    const float* x = (const float*)d_in[0];
    const float* W = (const float*)d_in[1];
    const float* b = (const float*)d_in[2];
    float* out = (float*)d_out;

    const int n_tokens = in_sizes[0] / DIM;      // 16384
    dim3 grid(n_tokens / 64);                    // 256 blocks
    dim3 block(512);                             // 8 waves

    if (ws_size >= 524288) {
        wsplit_kernel<<<dim3(64), dim3(256), 0, stream>>>(W, (_Float16*)d_ws);
        gate_mfma_kernel<true><<<grid, block, 0, stream>>>(x, W, b, out, (const _Float16*)d_ws);
    } else {
        gate_mfma_kernel<false><<<grid, block, 0, stream>>>(x, W, b, out, nullptr);
    }
}

// Round 6
// 214.390 us; speedup vs baseline: 2.3840x; 1.3282x over previous
//
#include <hip/hip_runtime.h>
#include <cfloat>

#define DIM 2048
#define NE  64

typedef _Float16 half8 __attribute__((ext_vector_type(8)));
typedef float    f32x4 __attribute__((ext_vector_type(4)));

struct Split { _Float16 hi, lo; };

// Split fp32 into fp16 hi + fp16 lo where x ≈ hi + lo/2048.
// hi clamped to 0 below fp16-min-normal so no denormal reaches the MFMA.
__device__ __forceinline__ Split split_f32(float x) {
    Split r;
    float h32;
    if (__builtin_fabsf(x) >= 6.103515625e-05f) {
        r.hi = (_Float16)x;          // v_cvt_f16_f32 (RTN)
        h32  = (float)r.hi;
    } else {
        r.hi = (_Float16)0.0f; h32 = 0.0f;
    }
    r.lo = (_Float16)((x - h32) * 2048.0f);
    return r;
}

// Pre-kernel: split W [64][2048] into fragment-ordered fp16 hi/lo in ws.
// hi element index: (sg*4 + nt)*64 + lane ; lo at +16384 (half8 units).
// Lane l of chunk (sg,nt) holds W[nt*16 + (l&15)][sg*32 + (l>>4)*8 + 0..7].
__global__ void wsplit_kernel(const float* __restrict__ W, _Float16* __restrict__ wsb) {
    int t    = blockIdx.x * 256 + threadIdx.x;   // 0..16383
    int lane = t & 63;
    int nt   = (t >> 6) & 3;
    int sg   = t >> 8;                           // k32-step 0..63
    int e    = nt * 16 + (lane & 15);
    int k    = sg * 32 + (lane >> 4) * 8;
    const float* wp = W + (size_t)e * DIM + k;
    half8 hi, lo;
    #pragma unroll
    for (int j = 0; j < 8; ++j) {
        Split s = split_f32(wp[j]);
        hi[j] = s.hi; lo[j] = s.lo;
    }
    ((half8*)wsb)[(size_t)((sg * 4 + nt) * 64 + lane)]         = hi;
    ((half8*)wsb)[(size_t)(16384 + (sg * 4 + nt) * 64 + lane)] = lo;
}

// Main: 1024 blocks x 256 thr (4 waves). Block = 16 tokens; wave w = K-quarter w
// (16 K32-steps). Explicit double-buffered register pipeline on A and B.
template <bool USE_WS>
__launch_bounds__(256, 2)
__global__ void gate_mfma_kernel(const float* __restrict__ x,
                                 const float* __restrict__ W,
                                 const float* __restrict__ b,
                                 float* __restrict__ out,
                                 const _Float16* __restrict__ wsb)
{
    __shared__ float sgrid[4][16][68];   // [k-quarter][token][expert], padded

    const int tid  = threadIdx.x;
    const int lane = tid & 63;
    const int wave = tid >> 6;           // k-quarter 0..3
    const int tokb = blockIdx.x * 16;
    const int row  = tokb + (lane & 15);

    const float* aptr = x + (size_t)row * DIM + wave * 512 + (lane >> 4) * 8;
    const half8* wb   = (const half8*)wsb;
    // element index for (s, nt): (wave*16+s)*256 + nt*64 + lane
    const int bbase = wave * 16 * 256 + lane;

    f32x4 acch[4], accc[4];
    #pragma unroll
    for (int nt = 0; nt < 4; ++nt) {
        acch[nt] = (f32x4){0.f, 0.f, 0.f, 0.f};
        accc[nt] = (f32x4){0.f, 0.f, 0.f, 0.f};
    }

    half8 Bh[2][4], Bl[2][4];
    f32x4 A0[2], A1[2];

    // ---- preload step 0 ----
    if (USE_WS) {
        #pragma unroll
        for (int nt = 0; nt < 4; ++nt) {
            Bh[0][nt] = wb[bbase + nt * 64];
            Bl[0][nt] = wb[16384 + bbase + nt * 64];
        }
    }
    A0[0] = *(const f32x4*)(aptr);
    A1[0] = *(const f32x4*)(aptr + 4);

    #pragma unroll
    for (int s = 0; s < 16; ++s) {
        const int cur = s & 1, nxt = cur ^ 1;

        // ---- issue next step's loads first (stay in flight over compute) ----
        if (s + 1 < 16) {
            if (USE_WS) {
                const int o = bbase + (s + 1) * 256;
                #pragma unroll
                for (int nt = 0; nt < 4; ++nt) {
                    Bh[nxt][nt] = wb[o + nt * 64];
                    Bl[nxt][nt] = wb[16384 + o + nt * 64];
                }
            }
            A0[nxt] = *(const f32x4*)(aptr + (s + 1) * 32);
            A1[nxt] = *(const f32x4*)(aptr + (s + 1) * 32 + 4);
        }

        // ---- split current A ----
        half8 Ah, Al;
        #pragma unroll
        for (int j = 0; j < 4; ++j) {
            Split sp = split_f32(A0[cur][j]);
            Ah[j] = sp.hi; Al[j] = sp.lo;
        }
        #pragma unroll
        for (int j = 0; j < 4; ++j) {
            Split sp = split_f32(A1[cur][j]);
            Ah[4 + j] = sp.hi; Al[4 + j] = sp.lo;
        }

        // ---- B for fallback path (no ws): load + split on demand ----
        half8 Bhc[4], Blc[4];
        if (USE_WS) {
            #pragma unroll
            for (int nt = 0; nt < 4; ++nt) { Bhc[nt] = Bh[cur][nt]; Blc[nt] = Bl[cur][nt]; }
        } else {
            const int sg = wave * 16 + s;
            #pragma unroll
            for (int nt = 0; nt < 4; ++nt) {
                const float* wp = W + (size_t)(nt * 16 + (lane & 15)) * DIM
                                    + sg * 32 + (lane >> 4) * 8;
                #pragma unroll
                for (int j = 0; j < 8; ++j) {
                    Split sp = split_f32(wp[j]);
                    Bhc[nt][j] = sp.hi; Blc[nt][j] = sp.lo;
                }
            }
        }

        // ---- 12 MFMAs ----
        #pragma unroll
        for (int nt = 0; nt < 4; ++nt) {
            acch[nt] = __builtin_amdgcn_mfma_f32_16x16x32_f16(Ah, Bhc[nt], acch[nt], 0, 0, 0);
            accc[nt] = __builtin_amdgcn_mfma_f32_16x16x32_f16(Al, Bhc[nt], accc[nt], 0, 0, 0);
            accc[nt] = __builtin_amdgcn_mfma_f32_16x16x32_f16(Ah, Blc[nt], accc[nt], 0, 0, 0);
        }
    }

    // ---- partial scores to LDS: D row=(lane>>4)*4+r (token), col=lane&15 (expert) ----
    #pragma unroll
    for (int nt = 0; nt < 4; ++nt)
        #pragma unroll
        for (int r = 0; r < 4; ++r) {
            int tl = (lane >> 4) * 4 + r;
            int e  = nt * 16 + (lane & 15);
            sgrid[wave][tl][e] = acch[nt][r] + accc[nt][r] * (1.0f / 2048.0f);
        }
    __syncthreads();

    // ---- per-token top-2 + renormalized softmax (proven epilogue) ----
    const float bias = b[lane];
    #pragma unroll
    for (int tt = 0; tt < 4; ++tt) {
        const int t = wave * 4 + tt;
        float s = sgrid[0][t][lane] + sgrid[1][t][lane]
                + sgrid[2][t][lane] + sgrid[3][t][lane] + bias;

        float v = s; int i = lane;
        #pragma unroll
        for (int off = 32; off > 0; off >>= 1) {
            float ov = __shfl_xor(v, off, 64);
            int   oi = __shfl_xor(i, off, 64);
            if (ov > v || (ov == v && oi < i)) { v = ov; i = oi; }
        }
        const float m1 = v; const int i1 = i;

        float s2 = (lane == i1) ? -FLT_MAX : s;
        v = s2; i = lane;
        #pragma unroll
        for (int off = 32; off > 0; off >>= 1) {
            float ov = __shfl_xor(v, off, 64);
            int   oi = __shfl_xor(i, off, 64);
            if (ov > v || (ov == v && oi < i)) { v = ov; i = oi; }
        }
        const float m2 = v; const int i2 = i;

        const float e_  = __expf(m2 - m1);
        const float inv = 1.f / (1.f + e_);
        const float outv = (lane == i1) ? inv : ((lane == i2) ? e_ * inv : 0.f);
        out[(size_t)(tokb + t) * NE + lane] = outv;
    }
}

extern "C" void kernel_launch(void* const* d_in, const int* in_sizes, int n_in,
                              void* d_out, int out_size, void* d_ws, size_t ws_size,
                              hipStream_t stream) {
    const float* x = (const float*)d_in[0];
    const float* W = (const float*)d_in[1];
    const float* b = (const float*)d_in[2];
    float* out = (float*)d_out;

    const int n_tokens = in_sizes[0] / DIM;      // 16384
    dim3 grid(n_tokens / 16);                    // 1024 blocks
    dim3 block(256);                             // 4 waves

    if (ws_size >= 524288) {
        wsplit_kernel<<<dim3(64), dim3(256), 0, stream>>>(W, (_Float16*)d_ws);
        gate_mfma_kernel<true><<<grid, block, 0, stream>>>(x, W, b, out, (const _Float16*)d_ws);
    } else {
        gate_mfma_kernel<false><<<grid, block, 0, stream>>>(x, W, b, out, nullptr);
    }
}